// Round 14
// baseline (90.383 us; speedup 1.0000x reference)
//
#include <hip/hip_runtime.h>
#include <math.h>

#define HIDDEN 256
#define NHEADS 8
#define HEAD 32
#define NTOK 2048      // tokens per batch (8*16*16)
#define NBIAS 115320   // 8 * 15 * 31 * 31
#define HTAB 14415     // 15*31*31 per-head bias entries

typedef __attribute__((ext_vector_type(8))) __bf16 bf16x8;
typedef __attribute__((ext_vector_type(4))) float f32x4;
typedef __attribute__((ext_vector_type(16))) float f32x16;
typedef __attribute__((ext_vector_type(4))) unsigned uint32x4;

static __device__ __forceinline__ f32x4 mfma16(bf16x8 a, bf16x8 b, f32x4 c) {
    return __builtin_amdgcn_mfma_f32_16x16x32_bf16(a, b, c, 0, 0, 0);
}
static __device__ __forceinline__ f32x16 mfma32(bf16x8 a, bf16x8 b, f32x16 c) {
    return __builtin_amdgcn_mfma_f32_32x32x16_bf16(a, b, c, 0, 0, 0);
}
static __device__ __forceinline__ float fexp2(float x) {
#if __has_builtin(__builtin_amdgcn_exp2f)
    return __builtin_amdgcn_exp2f(x);
#else
    return exp2f(x);
#endif
}
static __device__ __forceinline__ unsigned pkbf16(float a, float b) {
    unsigned short ua = __builtin_bit_cast(unsigned short, (__bf16)a);
    unsigned short ub = __builtin_bit_cast(unsigned short, (__bf16)b);
    return (unsigned)ua | ((unsigned)ub << 16);
}

// ---------------- kernel 0: fused input/weight conversion ----------------
__global__ void k_prep(const float* __restrict__ x, const float* __restrict__ w0,
                       const float* __restrict__ w1, const float* __restrict__ w2,
                       const float* __restrict__ w3, __bf16* __restrict__ xb,
                       __bf16* __restrict__ t0, __bf16* __restrict__ t1,
                       __bf16* __restrict__ t2, __bf16* __restrict__ t3) {
    int bid = blockIdx.x;
    if (bid < 2048) {
        int i = (bid * 256 + threadIdx.x) * 4;
        float4 v = *(const float4*)(x + i);
        xb[i + 0] = (__bf16)v.x;
        xb[i + 1] = (__bf16)v.y;
        xb[i + 2] = (__bf16)v.z;
        xb[i + 3] = (__bf16)v.w;
    } else {
        int q = bid - 2048;
        int wsel = q >> 8;
        int i = (q & 255) * 256 + threadIdx.x;
        const float* w = (wsel == 0) ? w0 : (wsel == 1) ? w1 : (wsel == 2) ? w2 : w3;
        __bf16* t = (wsel == 0) ? t0 : (wsel == 1) ? t1 : (wsel == 2) ? t2 : t3;
        int n = i >> 8, k = i & 255;
        t[i] = (__bf16)w[k * 256 + n];       // t[n][k] = W[k][n]
    }
}

// ---------------- kernel 1: fused QKV projection, 64x64 tile per 1-wave block --
// K/V in FRAGMENT-MAJOR tiled layouts (R7-verified); LDS-retiled coalesced stores.
__global__ __launch_bounds__(64) void k_qkv(const __bf16* __restrict__ xb,
                                            const __bf16* __restrict__ wqT,
                                            const __bf16* __restrict__ wkT,
                                            const __bf16* __restrict__ wvT,
                                            __bf16* __restrict__ qb,
                                            __bf16* __restrict__ kb,
                                            __bf16* __restrict__ vb) {
    int wid = blockIdx.x;                // 0..1535
    int lane = threadIdx.x;              // 0..63
    int ng = wid % 12, mt = wid / 12;    // mt 0..127
    int lm = lane & 15, lg = lane >> 4, lk = lg * 8;
    int which = ng >> 2;
    int nc0 = (ng & 3) * 64;
    const __bf16* wT = (which == 0) ? wqT : (which == 1) ? wkT : wvT;

    f32x4 acc[4][4];
#pragma unroll
    for (int m = 0; m < 4; ++m)
#pragma unroll
        for (int n = 0; n < 4; ++n) acc[m][n] = (f32x4){0.f, 0.f, 0.f, 0.f};

    const __bf16* arow = xb + (size_t)(mt * 64 + lm) * 256 + lk;
    const __bf16* brow = wT + (size_t)(nc0 + lm) * 256 + lk;
#pragma unroll
    for (int kk = 0; kk < 8; ++kk) {
        bf16x8 a[4], b[4];
#pragma unroll
        for (int m = 0; m < 4; ++m) a[m] = *(const bf16x8*)(arow + (size_t)m * 16 * 256 + kk * 32);
#pragma unroll
        for (int n = 0; n < 4; ++n) b[n] = *(const bf16x8*)(brow + (size_t)n * 16 * 256 + kk * 32);
#pragma unroll
        for (int m = 0; m < 4; ++m)
#pragma unroll
            for (int n = 0; n < 4; ++n) acc[m][n] = mfma16(a[m], b[n], acc[m][n]);
    }

    int b_ = mt >> 5;
    int tb = (mt & 31) * 2;
    int h0 = nc0 >> 5;

    __shared__ __attribute__((aligned(16))) __bf16 tile[4608];   // 64 x 72

    if (which == 0) {
        const float QS = 0.17677669529663687f * 1.4426950408889634f;  // 1/sqrt(32)*log2e
#pragma unroll
        for (int m = 0; m < 4; ++m)
#pragma unroll
            for (int n = 0; n < 4; ++n) {
                int col = nc0 + n * 16 + lm;
                int h = col >> 5, d = col & 31;
#pragma unroll
                for (int r = 0; r < 4; ++r) {
                    int row = mt * 64 + m * 16 + lg * 4 + r;
                    qb[(size_t)(b_ * 8 + h) * 65536 + (size_t)(row & 2047) * 32 + d] =
                        (__bf16)(acc[m][n][r] * QS);
                }
            }
        return;
    }

#pragma unroll
    for (int m = 0; m < 4; ++m)
#pragma unroll
        for (int n = 0; n < 4; ++n)
#pragma unroll
            for (int r = 0; r < 4; ++r) {
                int row = m * 16 + lg * 4 + r;
                int col = n * 16 + lm;
                if (which == 1) tile[row * 72 + col] = (__bf16)acc[m][n][r];
                else            tile[col * 72 + row] = (__bf16)acc[m][n][r];
            }
    __syncthreads();

    if (which == 1) {
#pragma unroll
        for (int tl = 0; tl < 2; ++tl)
#pragma unroll
            for (int hl = 0; hl < 2; ++hl) {
                size_t gb = (size_t)(b_ * 8 + h0 + hl) * 65536 + (size_t)(tb + tl) * 1024;
#pragma unroll
                for (int half = 0; half < 2; ++half) {
                    int u = half * 64 + lane;
                    int j = u >> 6, hf2 = (u >> 5) & 1, lq2 = u & 31;
                    bf16x8 vv = *(const bf16x8*)&tile[(tl * 32 + lq2) * 72 + hl * 32 + 16 * j + 8 * hf2];
                    *(bf16x8*)(kb + gb + (size_t)u * 8) = vv;
                }
            }
    } else {
#pragma unroll
        for (int tl = 0; tl < 2; ++tl)
#pragma unroll
            for (int hl = 0; hl < 2; ++hl) {
                size_t gb = (size_t)(b_ * 8 + h0 + hl) * 65536 + (size_t)(tb + tl) * 1024;
#pragma unroll
                for (int half = 0; half < 2; ++half) {
                    int u0 = (half * 64 + lane) * 2;
                    int g = u0 >> 6, hf2 = (u0 >> 5) & 1, d0 = u0 & 31;
                    const __bf16* pl = &tile[(hl * 32 + d0) * 72 + tl * 32 + 8 * g + 4 * hf2];
                    uint2 lo = *(const uint2*)pl;
                    uint2 hi = *(const uint2*)(pl + 72);
                    uint32x4 sv = {lo.x, lo.y, hi.x, hi.y};
                    *(uint32x4*)(vb + gb + (size_t)u0 * 4) = sv;
                }
            }
    }
}

// ---------------- kernel 2: attention, 8-wave k-split (512 thr), 64q/block -----
// R14: same math/state as the R10/R13 kernel, but 8 waves each cover k-range 256
// (8 iters) -> 24 waves/CU resident (vs 16), attacking the TLP starvation the
// counters show (no pipe >50% busy). part[] = [8][64][17]; waves 0-3 reduce/store.
__global__ __launch_bounds__(512) void k_attn(const __bf16* __restrict__ qb,
                                              const __bf16* __restrict__ kb,
                                              const __bf16* __restrict__ vb,
                                              const float* __restrict__ bias,
                                              __bf16* __restrict__ attn) {
    int i = blockIdx.x;
    int x = i & 7, r_ = i >> 3;          // XCD x serves bh {x,x+8,x+16,x+24}
    int bh = x + ((r_ >> 5) << 3);
    int qblk = r_ & 31;
    int b_ = bh >> 3, h = bh & 7;
    int w = threadIdx.x >> 6;            // wave = k-eighth, 0..7
    int lane = threadIdx.x & 63;
    int lq = lane & 31;
    int hf = lane >> 5;
    int q0 = qblk * 64;

    __shared__ float smem[8704];   // max(bias 5016, part 8*64*17=8704) floats

    {
        int qd = q0 >> 8, qh0 = (q0 >> 4) & 15;
        const float* bt = bias + h * HTAB;
        for (int t = threadIdx.x; t < 5016; t += 512) {
            int dd = t / 627, rem = t - dd * 627;
            int hh = rem / 33, ww = rem - hh * 33;
            int dw = 30 - ww; if (dw < 0) dw = 0;
            smem[t] = bt[(qd + dd) * 961 + (qh0 + hh) * 31 + dw] * 1.4426950408889634f;
        }
    }
    __syncthreads();

    const __bf16* qbase = qb + (size_t)bh * NTOK * 32;
    const __bf16* kbase = kb + (size_t)bh * NTOK * 32;
    const __bf16* vbase = vb + (size_t)bh * NTOK * 32;

    bf16x8 qfA0 = *(const bf16x8*)(qbase + (size_t)(q0 + lq) * 32 + hf * 8);
    bf16x8 qfA1 = *(const bf16x8*)(qbase + (size_t)(q0 + lq) * 32 + 16 + hf * 8);
    bf16x8 qfB0 = *(const bf16x8*)(qbase + (size_t)(q0 + 32 + lq) * 32 + hf * 8);
    bf16x8 qfB1 = *(const bf16x8*)(qbase + (size_t)(q0 + 32 + lq) * 32 + 16 + hf * 8);

    int lbase = (lq >> 4) * 33 + 15 - (lq & 15) + 4 * hf;

    f32x16 OaccA, LaccA, OaccB, LaccB;
#pragma unroll
    for (int j = 0; j < 16; ++j) { OaccA[j] = 0.f; LaccA[j] = 0.f; OaccB[j] = 0.f; LaccB[j] = 0.f; }

    bf16x8 ones;
#pragma unroll
    for (int j = 0; j < 8; ++j) ones[j] = (__bf16)1.0f;

    // K-frag pipeline registers (wave w starts at tile tt = w*8)
    bf16x8 ck0, ck1;
    {
        const __bf16* kt = kbase + ((size_t)(w * 8) * 128 + lane) * 8;
        ck0 = *(const bf16x8*)(kt);
        ck1 = *(const bf16x8*)(kt + 512);
    }

#pragma unroll
    for (int it = 0; it < 8; ++it) {
        int t0 = w * 256 + it * 32;
        int tt = t0 >> 5;

        // prefetch next K frags
        bf16x8 nk0, nk1;
        if (it < 7) {
            const __bf16* kt1 = kbase + ((size_t)(tt + 1) * 128 + lane) * 8;
            nk0 = *(const bf16x8*)(kt1);
            nk1 = *(const bf16x8*)(kt1 + 512);
        }

        // V frags (contiguous), shared by both strips
        const __bf16* vt = vbase + ((size_t)tt * 256 + lane) * 4;
        uint2 va  = *(const uint2*)(vt);
        uint2 vbq = *(const uint2*)(vt + 256);
        uint2 vc  = *(const uint2*)(vt + 512);
        uint2 vd  = *(const uint2*)(vt + 768);
        uint32x4 vw0 = {va.x, va.y, vbq.x, vbq.y};
        uint32x4 vw1 = {vc.x, vc.y, vd.x, vd.y};
        bf16x8 vf0 = __builtin_bit_cast(bf16x8, vw0);
        bf16x8 vf1 = __builtin_bit_cast(bf16x8, vw1);

        // bias C-init from LDS (inline)
        int kd = t0 >> 8, kh0 = (t0 >> 4) & 15;
        int a0 = (7 - kd) * 627 + (15 - kh0) * 33 + lbase;
        f32x16 SA, SB;
#pragma unroll
        for (int r = 0; r < 4; ++r) {
            SA[r]      = smem[a0 + r];
            SA[4 + r]  = smem[a0 + 8 + r];
            SA[8 + r]  = smem[a0 - 33 + r];
            SA[12 + r] = smem[a0 - 25 + r];
            SB[r]      = smem[a0 + 66 + r];
            SB[4 + r]  = smem[a0 + 74 + r];
            SB[8 + r]  = smem[a0 + 33 + r];
            SB[12 + r] = smem[a0 + 41 + r];
        }
        SA = mfma32(ck0, qfA0, SA);
        SA = mfma32(ck1, qfA1, SA);
        SB = mfma32(ck0, qfB0, SB);
        SB = mfma32(ck1, qfB1, SB);

        // strip A
        {
            unsigned W0 = pkbf16(fexp2(SA[0]),  fexp2(SA[1]));
            unsigned W1 = pkbf16(fexp2(SA[2]),  fexp2(SA[3]));
            unsigned W2 = pkbf16(fexp2(SA[4]),  fexp2(SA[5]));
            unsigned W3 = pkbf16(fexp2(SA[6]),  fexp2(SA[7]));
            unsigned W4 = pkbf16(fexp2(SA[8]),  fexp2(SA[9]));
            unsigned W5 = pkbf16(fexp2(SA[10]), fexp2(SA[11]));
            unsigned W6 = pkbf16(fexp2(SA[12]), fexp2(SA[13]));
            unsigned W7 = pkbf16(fexp2(SA[14]), fexp2(SA[15]));
            uint32x4 pw0 = {W0, W1, W2, W3};
            uint32x4 pw1 = {W4, W5, W6, W7};
            bf16x8 pf0 = __builtin_bit_cast(bf16x8, pw0);
            bf16x8 pf1 = __builtin_bit_cast(bf16x8, pw1);
            OaccA = mfma32(vf0, pf0, OaccA);
            OaccA = mfma32(vf1, pf1, OaccA);
            LaccA = mfma32(ones, pf0, LaccA);
            LaccA = mfma32(ones, pf1, LaccA);
        }
        // strip B
        {
            unsigned W0 = pkbf16(fexp2(SB[0]),  fexp2(SB[1]));
            unsigned W1 = pkbf16(fexp2(SB[2]),  fexp2(SB[3]));
            unsigned W2 = pkbf16(fexp2(SB[4]),  fexp2(SB[5]));
            unsigned W3 = pkbf16(fexp2(SB[6]),  fexp2(SB[7]));
            unsigned W4 = pkbf16(fexp2(SB[8]),  fexp2(SB[9]));
            unsigned W5 = pkbf16(fexp2(SB[10]), fexp2(SB[11]));
            unsigned W6 = pkbf16(fexp2(SB[12]), fexp2(SB[13]));
            unsigned W7 = pkbf16(fexp2(SB[14]), fexp2(SB[15]));
            uint32x4 pw0 = {W0, W1, W2, W3};
            uint32x4 pw1 = {W4, W5, W6, W7};
            bf16x8 pf0 = __builtin_bit_cast(bf16x8, pw0);
            bf16x8 pf1 = __builtin_bit_cast(bf16x8, pw1);
            OaccB = mfma32(vf0, pf0, OaccB);
            OaccB = mfma32(vf1, pf1, OaccB);
            LaccB = mfma32(ones, pf0, LaccB);
            LaccB = mfma32(ones, pf1, LaccB);
        }

        if (it < 7) { ck0 = nk0; ck1 = nk1; }
    }

    // ---- combine 8 k-partials via LDS (reuse smem as part[8][64][17]) ----
    float (*part)[64][17] = (float (*)[64][17])smem;
#pragma unroll
    for (int s = 0; s < 2; ++s) {
        f32x16* O = s ? &OaccB : &OaccA;
        f32x16* L = s ? &LaccB : &LaccA;
        __syncthreads();
#pragma unroll
        for (int j = 0; j < 4; ++j) {
            float4 t;
            t.x = (*O)[4 * j]; t.y = (*O)[4 * j + 1]; t.z = (*O)[4 * j + 2]; t.w = (*O)[4 * j + 3];
            *(float4*)&part[w][lane][4 * j] = t;
        }
        part[w][lane][16] = (*L)[0];
        __syncthreads();

        if (w < 4) {
            float4 o = {0.f, 0.f, 0.f, 0.f};
            float ls = 0.f;
#pragma unroll
            for (int sw = 0; sw < 8; ++sw) {
                float4 t = *(const float4*)&part[sw][lane][4 * w];
                o.x += t.x; o.y += t.y; o.z += t.z; o.w += t.w;
                ls += part[sw][lane][16];
            }
            float inv = 1.0f / ls;
            unsigned lo = pkbf16(o.x * inv, o.y * inv);
            unsigned hi = pkbf16(o.z * inv, o.w * inv);
            size_t base = ((size_t)b_ * NTOK + q0 + 32 * s + lq) * 256 + h * 32 + 8 * w + 4 * hf;
            *(uint2*)(attn + base) = make_uint2(lo, hi);
        }
    }
}

// ---------------- kernel 3: output projection -> fp32, 32x64 tile per wave ------
__global__ __launch_bounds__(256) void k_out(const __bf16* __restrict__ attn,
                                             const __bf16* __restrict__ woT,
                                             float* __restrict__ out) {
    int wid = blockIdx.x * 4 + (threadIdx.x >> 6);   // 0..1023
    int lane = threadIdx.x & 63;
    int ng = wid & 3, mt = wid >> 2;                 // mt 0..255
    int lm = lane & 15, lg = lane >> 4, lk = lg * 8;
    int nc0 = ng * 64;

    f32x4 acc[2][4];
#pragma unroll
    for (int m = 0; m < 2; ++m)
#pragma unroll
        for (int n = 0; n < 4; ++n) acc[m][n] = (f32x4){0.f, 0.f, 0.f, 0.f};

    const __bf16* arow = attn + (size_t)(mt * 32 + lm) * 256 + lk;
    const __bf16* brow = woT + (size_t)(nc0 + lm) * 256 + lk;
#pragma unroll
    for (int kk = 0; kk < 8; ++kk) {
        bf16x8 a[2], b[4];
#pragma unroll
        for (int m = 0; m < 2; ++m) a[m] = *(const bf16x8*)(arow + (size_t)m * 16 * 256 + kk * 32);
#pragma unroll
        for (int n = 0; n < 4; ++n) b[n] = *(const bf16x8*)(brow + (size_t)n * 16 * 256 + kk * 32);
#pragma unroll
        for (int m = 0; m < 2; ++m)
#pragma unroll
            for (int n = 0; n < 4; ++n) acc[m][n] = mfma16(a[m], b[n], acc[m][n]);
    }
#pragma unroll
    for (int m = 0; m < 2; ++m) {
#pragma unroll
        for (int n = 0; n < 4; ++n) {
            int col = nc0 + n * 16 + lm;
#pragma unroll
            for (int r = 0; r < 4; ++r) {
                int row = mt * 32 + m * 16 + lg * 4 + r;
                out[(size_t)row * 256 + col] = acc[m][n][r];
            }
        }
    }
}

extern "C" void kernel_launch(void* const* d_in, const int* in_sizes, int n_in,
                              void* d_out, int out_size, void* d_ws, size_t ws_size,
                              hipStream_t stream) {
    const float* x    = (const float*)d_in[0];
    const float* Wq   = (const float*)d_in[1];
    const float* Wk   = (const float*)d_in[2];
    const float* Wv   = (const float*)d_in[3];
    const float* Wo   = (const float*)d_in[4];
    const float* bias = (const float*)d_in[5];
    float* out = (float*)d_out;

    __bf16* ws  = (__bf16*)d_ws;
    __bf16* xb  = ws;                       // 2,097,152 bf16 (reused as att)
    __bf16* wqT = xb  + 2097152;
    __bf16* wkT = wqT + 65536;
    __bf16* wvT = wkT + 65536;
    __bf16* woT = wvT + 65536;
    __bf16* qb  = woT + 65536;              // (b,h,n,32)
    __bf16* kb  = qb  + 2097152;            // (b,h) fragment-major K tiles
    __bf16* vb  = kb  + 2097152;            // (b,h) fragment-major V tiles
    __bf16* att = xb;                       // alias: xb dead after k_qkv

    k_prep<<<3072, 256, 0, stream>>>(x, Wq, Wk, Wv, Wo, xb, wqT, wkT, wvT, woT);
    k_qkv<<<1536, 64, 0, stream>>>(xb, wqT, wkT, wvT, qb, kb, vb);
    k_attn<<<1024, 512, 0, stream>>>(qb, kb, vb, bias, att);
    k_out<<<256, 256, 0, stream>>>(att, woT, out);
}

// Round 15
// 77.702 us; speedup vs baseline: 1.1632x; 1.1632x over previous
//
#include <hip/hip_runtime.h>
#include <math.h>

#define HIDDEN 256
#define NHEADS 8
#define HEAD 32
#define NTOK 2048      // tokens per batch (8*16*16)
#define NBIAS 115320   // 8 * 15 * 31 * 31
#define HTAB 14415     // 15*31*31 per-head bias entries

typedef __attribute__((ext_vector_type(8))) __bf16 bf16x8;
typedef __attribute__((ext_vector_type(4))) float f32x4;
typedef __attribute__((ext_vector_type(16))) float f32x16;
typedef __attribute__((ext_vector_type(4))) unsigned uint32x4;

static __device__ __forceinline__ f32x4 mfma16(bf16x8 a, bf16x8 b, f32x4 c) {
    return __builtin_amdgcn_mfma_f32_16x16x32_bf16(a, b, c, 0, 0, 0);
}
static __device__ __forceinline__ f32x16 mfma32(bf16x8 a, bf16x8 b, f32x16 c) {
    return __builtin_amdgcn_mfma_f32_32x32x16_bf16(a, b, c, 0, 0, 0);
}
static __device__ __forceinline__ float fexp2(float x) {
#if __has_builtin(__builtin_amdgcn_exp2f)
    return __builtin_amdgcn_exp2f(x);
#else
    return exp2f(x);
#endif
}
static __device__ __forceinline__ unsigned pkbf16(float a, float b) {
    unsigned short ua = __builtin_bit_cast(unsigned short, (__bf16)a);
    unsigned short ub = __builtin_bit_cast(unsigned short, (__bf16)b);
    return (unsigned)ua | ((unsigned)ub << 16);
}

// ---------------- kernel 0: fused input/weight conversion ----------------
__global__ void k_prep(const float* __restrict__ x, const float* __restrict__ w0,
                       const float* __restrict__ w1, const float* __restrict__ w2,
                       const float* __restrict__ w3, __bf16* __restrict__ xb,
                       __bf16* __restrict__ t0, __bf16* __restrict__ t1,
                       __bf16* __restrict__ t2, __bf16* __restrict__ t3) {
    int bid = blockIdx.x;
    if (bid < 2048) {
        int i = (bid * 256 + threadIdx.x) * 4;
        float4 v = *(const float4*)(x + i);
        uint2 pk = make_uint2(pkbf16(v.x, v.y), pkbf16(v.z, v.w));
        *(uint2*)(xb + i) = pk;                         // one 8B store (was 4x2B)
    } else {
        int q = bid - 2048;
        int wsel = q >> 8;
        int i = (q & 255) * 256 + threadIdx.x;
        const float* w = (wsel == 0) ? w0 : (wsel == 1) ? w1 : (wsel == 2) ? w2 : w3;
        __bf16* t = (wsel == 0) ? t0 : (wsel == 1) ? t1 : (wsel == 2) ? t2 : t3;
        int n = i >> 8, k = i & 255;
        t[i] = (__bf16)w[k * 256 + n];       // t[n][k] = W[k][n]
    }
}

// ---------------- kernel 1: fused QKV projection, 64x64 tile per 1-wave block --
// K/V in FRAGMENT-MAJOR tiled layouts (R7-verified); LDS-retiled coalesced stores.
__global__ __launch_bounds__(64) void k_qkv(const __bf16* __restrict__ xb,
                                            const __bf16* __restrict__ wqT,
                                            const __bf16* __restrict__ wkT,
                                            const __bf16* __restrict__ wvT,
                                            __bf16* __restrict__ qb,
                                            __bf16* __restrict__ kb,
                                            __bf16* __restrict__ vb) {
    int wid = blockIdx.x;                // 0..1535
    int lane = threadIdx.x;              // 0..63
    int ng = wid % 12, mt = wid / 12;    // mt 0..127
    int lm = lane & 15, lg = lane >> 4, lk = lg * 8;
    int which = ng >> 2;
    int nc0 = (ng & 3) * 64;
    const __bf16* wT = (which == 0) ? wqT : (which == 1) ? wkT : wvT;

    f32x4 acc[4][4];
#pragma unroll
    for (int m = 0; m < 4; ++m)
#pragma unroll
        for (int n = 0; n < 4; ++n) acc[m][n] = (f32x4){0.f, 0.f, 0.f, 0.f};

    const __bf16* arow = xb + (size_t)(mt * 64 + lm) * 256 + lk;
    const __bf16* brow = wT + (size_t)(nc0 + lm) * 256 + lk;
#pragma unroll
    for (int kk = 0; kk < 8; ++kk) {
        bf16x8 a[4], b[4];
#pragma unroll
        for (int m = 0; m < 4; ++m) a[m] = *(const bf16x8*)(arow + (size_t)m * 16 * 256 + kk * 32);
#pragma unroll
        for (int n = 0; n < 4; ++n) b[n] = *(const bf16x8*)(brow + (size_t)n * 16 * 256 + kk * 32);
#pragma unroll
        for (int m = 0; m < 4; ++m)
#pragma unroll
            for (int n = 0; n < 4; ++n) acc[m][n] = mfma16(a[m], b[n], acc[m][n]);
    }

    int b_ = mt >> 5;
    int tb = (mt & 31) * 2;
    int h0 = nc0 >> 5;

    __shared__ __attribute__((aligned(16))) __bf16 tile[4608];   // 64 x 72

    if (which == 0) {
        const float QS = 0.17677669529663687f * 1.4426950408889634f;  // 1/sqrt(32)*log2e
#pragma unroll
        for (int m = 0; m < 4; ++m)
#pragma unroll
            for (int n = 0; n < 4; ++n) {
                int col = nc0 + n * 16 + lm;
                int h = col >> 5, d = col & 31;
#pragma unroll
                for (int r = 0; r < 4; ++r) {
                    int row = mt * 64 + m * 16 + lg * 4 + r;
                    qb[(size_t)(b_ * 8 + h) * 65536 + (size_t)(row & 2047) * 32 + d] =
                        (__bf16)(acc[m][n][r] * QS);
                }
            }
        return;
    }

#pragma unroll
    for (int m = 0; m < 4; ++m)
#pragma unroll
        for (int n = 0; n < 4; ++n)
#pragma unroll
            for (int r = 0; r < 4; ++r) {
                int row = m * 16 + lg * 4 + r;
                int col = n * 16 + lm;
                if (which == 1) tile[row * 72 + col] = (__bf16)acc[m][n][r];
                else            tile[col * 72 + row] = (__bf16)acc[m][n][r];
            }
    __syncthreads();

    if (which == 1) {
#pragma unroll
        for (int tl = 0; tl < 2; ++tl)
#pragma unroll
            for (int hl = 0; hl < 2; ++hl) {
                size_t gb = (size_t)(b_ * 8 + h0 + hl) * 65536 + (size_t)(tb + tl) * 1024;
#pragma unroll
                for (int half = 0; half < 2; ++half) {
                    int u = half * 64 + lane;
                    int j = u >> 6, hf2 = (u >> 5) & 1, lq2 = u & 31;
                    bf16x8 vv = *(const bf16x8*)&tile[(tl * 32 + lq2) * 72 + hl * 32 + 16 * j + 8 * hf2];
                    *(bf16x8*)(kb + gb + (size_t)u * 8) = vv;
                }
            }
    } else {
#pragma unroll
        for (int tl = 0; tl < 2; ++tl)
#pragma unroll
            for (int hl = 0; hl < 2; ++hl) {
                size_t gb = (size_t)(b_ * 8 + h0 + hl) * 65536 + (size_t)(tb + tl) * 1024;
#pragma unroll
                for (int half = 0; half < 2; ++half) {
                    int u0 = (half * 64 + lane) * 2;
                    int g = u0 >> 6, hf2 = (u0 >> 5) & 1, d0 = u0 & 31;
                    const __bf16* pl = &tile[(hl * 32 + d0) * 72 + tl * 32 + 8 * g + 4 * hf2];
                    uint2 lo = *(const uint2*)pl;
                    uint2 hi = *(const uint2*)(pl + 72);
                    uint32x4 sv = {lo.x, lo.y, hi.x, hi.y};
                    *(uint32x4*)(vb + gb + (size_t)u0 * 4) = sv;
                }
            }
    }
}

// ---------------- kernel 2: attention (R13 structure + T5 setprio) --------------
// Block = (b,h, 64 queries); wave = k-quarter x both strips; K/V frags shared.
// Main loop is barrier-free -> waves independent -> m191 setprio regime.
__global__ __launch_bounds__(256) void k_attn(const __bf16* __restrict__ qb,
                                              const __bf16* __restrict__ kb,
                                              const __bf16* __restrict__ vb,
                                              const float* __restrict__ bias,
                                              __bf16* __restrict__ attn) {
    int i = blockIdx.x;
    int x = i & 7, r_ = i >> 3;          // XCD x serves bh {x,x+8,x+16,x+24}
    int bh = x + ((r_ >> 5) << 3);
    int qblk = r_ & 31;
    int b_ = bh >> 3, h = bh & 7;
    int w = threadIdx.x >> 6;
    int lane = threadIdx.x & 63;
    int lq = lane & 31;
    int hf = lane >> 5;
    int q0 = qblk * 64;

    __shared__ float smem[5016];   // bias slice 8*19*33; unions part[4][64][17]=4352

    {
        int qd = q0 >> 8, qh0 = (q0 >> 4) & 15;
        const float* bt = bias + h * HTAB;
        for (int t = threadIdx.x; t < 5016; t += 256) {
            int dd = t / 627, rem = t - dd * 627;
            int hh = rem / 33, ww = rem - hh * 33;
            int dw = 30 - ww; if (dw < 0) dw = 0;
            smem[t] = bt[(qd + dd) * 961 + (qh0 + hh) * 31 + dw] * 1.4426950408889634f;
        }
    }
    __syncthreads();

    const __bf16* qbase = qb + (size_t)bh * NTOK * 32;
    const __bf16* kbase = kb + (size_t)bh * NTOK * 32;
    const __bf16* vbase = vb + (size_t)bh * NTOK * 32;

    bf16x8 qfA0 = *(const bf16x8*)(qbase + (size_t)(q0 + lq) * 32 + hf * 8);
    bf16x8 qfA1 = *(const bf16x8*)(qbase + (size_t)(q0 + lq) * 32 + 16 + hf * 8);
    bf16x8 qfB0 = *(const bf16x8*)(qbase + (size_t)(q0 + 32 + lq) * 32 + hf * 8);
    bf16x8 qfB1 = *(const bf16x8*)(qbase + (size_t)(q0 + 32 + lq) * 32 + 16 + hf * 8);

    int lbase = (lq >> 4) * 33 + 15 - (lq & 15) + 4 * hf;

    f32x16 OaccA, LaccA, OaccB, LaccB;
#pragma unroll
    for (int j = 0; j < 16; ++j) { OaccA[j] = 0.f; LaccA[j] = 0.f; OaccB[j] = 0.f; LaccB[j] = 0.f; }

    bf16x8 ones;
#pragma unroll
    for (int j = 0; j < 8; ++j) ones[j] = (__bf16)1.0f;

    // K-frag pipeline registers
    bf16x8 ck0, ck1;
    {
        const __bf16* kt = kbase + ((size_t)(w * 16) * 128 + lane) * 8;
        ck0 = *(const bf16x8*)(kt);
        ck1 = *(const bf16x8*)(kt + 512);
    }

#pragma unroll
    for (int it = 0; it < 16; ++it) {
        int t0 = w * 512 + it * 32;
        int tt = t0 >> 5;

        // prefetch next K frags
        bf16x8 nk0, nk1;
        if (it < 15) {
            const __bf16* kt1 = kbase + ((size_t)(tt + 1) * 128 + lane) * 8;
            nk0 = *(const bf16x8*)(kt1);
            nk1 = *(const bf16x8*)(kt1 + 512);
        }

        // V frags (contiguous), shared by both strips
        const __bf16* vt = vbase + ((size_t)tt * 256 + lane) * 4;
        uint2 va  = *(const uint2*)(vt);
        uint2 vbq = *(const uint2*)(vt + 256);
        uint2 vc  = *(const uint2*)(vt + 512);
        uint2 vd  = *(const uint2*)(vt + 768);
        uint32x4 vw0 = {va.x, va.y, vbq.x, vbq.y};
        uint32x4 vw1 = {vc.x, vc.y, vd.x, vd.y};
        bf16x8 vf0 = __builtin_bit_cast(bf16x8, vw0);
        bf16x8 vf1 = __builtin_bit_cast(bf16x8, vw1);

        // bias C-init from LDS (inline)
        int kd = t0 >> 8, kh0 = (t0 >> 4) & 15;
        int a0 = (7 - kd) * 627 + (15 - kh0) * 33 + lbase;
        f32x16 SA, SB;
#pragma unroll
        for (int r = 0; r < 4; ++r) {
            SA[r]      = smem[a0 + r];
            SA[4 + r]  = smem[a0 + 8 + r];
            SA[8 + r]  = smem[a0 - 33 + r];
            SA[12 + r] = smem[a0 - 25 + r];
            SB[r]      = smem[a0 + 66 + r];
            SB[4 + r]  = smem[a0 + 74 + r];
            SB[8 + r]  = smem[a0 + 33 + r];
            SB[12 + r] = smem[a0 + 41 + r];
        }
        __builtin_amdgcn_s_setprio(1);
        SA = mfma32(ck0, qfA0, SA);
        SA = mfma32(ck1, qfA1, SA);
        SB = mfma32(ck0, qfB0, SB);
        SB = mfma32(ck1, qfB1, SB);
        __builtin_amdgcn_s_setprio(0);

        // strip A
        {
            unsigned W0 = pkbf16(fexp2(SA[0]),  fexp2(SA[1]));
            unsigned W1 = pkbf16(fexp2(SA[2]),  fexp2(SA[3]));
            unsigned W2 = pkbf16(fexp2(SA[4]),  fexp2(SA[5]));
            unsigned W3 = pkbf16(fexp2(SA[6]),  fexp2(SA[7]));
            unsigned W4 = pkbf16(fexp2(SA[8]),  fexp2(SA[9]));
            unsigned W5 = pkbf16(fexp2(SA[10]), fexp2(SA[11]));
            unsigned W6 = pkbf16(fexp2(SA[12]), fexp2(SA[13]));
            unsigned W7 = pkbf16(fexp2(SA[14]), fexp2(SA[15]));
            uint32x4 pw0 = {W0, W1, W2, W3};
            uint32x4 pw1 = {W4, W5, W6, W7};
            bf16x8 pf0 = __builtin_bit_cast(bf16x8, pw0);
            bf16x8 pf1 = __builtin_bit_cast(bf16x8, pw1);
            __builtin_amdgcn_s_setprio(1);
            OaccA = mfma32(vf0, pf0, OaccA);
            OaccA = mfma32(vf1, pf1, OaccA);
            LaccA = mfma32(ones, pf0, LaccA);
            LaccA = mfma32(ones, pf1, LaccA);
            __builtin_amdgcn_s_setprio(0);
        }
        // strip B
        {
            unsigned W0 = pkbf16(fexp2(SB[0]),  fexp2(SB[1]));
            unsigned W1 = pkbf16(fexp2(SB[2]),  fexp2(SB[3]));
            unsigned W2 = pkbf16(fexp2(SB[4]),  fexp2(SB[5]));
            unsigned W3 = pkbf16(fexp2(SB[6]),  fexp2(SB[7]));
            unsigned W4 = pkbf16(fexp2(SB[8]),  fexp2(SB[9]));
            unsigned W5 = pkbf16(fexp2(SB[10]), fexp2(SB[11]));
            unsigned W6 = pkbf16(fexp2(SB[12]), fexp2(SB[13]));
            unsigned W7 = pkbf16(fexp2(SB[14]), fexp2(SB[15]));
            uint32x4 pw0 = {W0, W1, W2, W3};
            uint32x4 pw1 = {W4, W5, W6, W7};
            bf16x8 pf0 = __builtin_bit_cast(bf16x8, pw0);
            bf16x8 pf1 = __builtin_bit_cast(bf16x8, pw1);
            __builtin_amdgcn_s_setprio(1);
            OaccB = mfma32(vf0, pf0, OaccB);
            OaccB = mfma32(vf1, pf1, OaccB);
            LaccB = mfma32(ones, pf0, LaccB);
            LaccB = mfma32(ones, pf1, LaccB);
            __builtin_amdgcn_s_setprio(0);
        }

        if (it < 15) { ck0 = nk0; ck1 = nk1; }
    }

    // ---- combine 4 k-partials via LDS (reuse smem as part[4][64][17]) ----
    float (*part)[64][17] = (float (*)[64][17])smem;
#pragma unroll
    for (int s = 0; s < 2; ++s) {
        f32x16* O = s ? &OaccB : &OaccA;
        f32x16* L = s ? &LaccB : &LaccA;
        __syncthreads();
#pragma unroll
        for (int j = 0; j < 4; ++j) {
            float4 t;
            t.x = (*O)[4 * j]; t.y = (*O)[4 * j + 1]; t.z = (*O)[4 * j + 2]; t.w = (*O)[4 * j + 3];
            *(float4*)&part[w][lane][4 * j] = t;
        }
        part[w][lane][16] = (*L)[0];
        __syncthreads();

        float4 o = {0.f, 0.f, 0.f, 0.f};
        float ls = 0.f;
#pragma unroll
        for (int sw = 0; sw < 4; ++sw) {
            float4 t = *(const float4*)&part[sw][lane][4 * w];
            o.x += t.x; o.y += t.y; o.z += t.z; o.w += t.w;
            ls += part[sw][lane][16];
        }
        float inv = 1.0f / ls;
        unsigned lo = pkbf16(o.x * inv, o.y * inv);
        unsigned hi = pkbf16(o.z * inv, o.w * inv);
        size_t base = ((size_t)b_ * NTOK + q0 + 32 * s + lq) * 256 + h * 32 + 8 * w + 4 * hf;
        *(uint2*)(attn + base) = make_uint2(lo, hi);
    }
}

// ---------------- kernel 3: output projection -> fp32, 32x64 tile per wave ------
__global__ __launch_bounds__(256) void k_out(const __bf16* __restrict__ attn,
                                             const __bf16* __restrict__ woT,
                                             float* __restrict__ out) {
    int wid = blockIdx.x * 4 + (threadIdx.x >> 6);   // 0..1023
    int lane = threadIdx.x & 63;
    int ng = wid & 3, mt = wid >> 2;                 // mt 0..255
    int lm = lane & 15, lg = lane >> 4, lk = lg * 8;
    int nc0 = ng * 64;

    f32x4 acc[2][4];
#pragma unroll
    for (int m = 0; m < 2; ++m)
#pragma unroll
        for (int n = 0; n < 4; ++n) acc[m][n] = (f32x4){0.f, 0.f, 0.f, 0.f};

    const __bf16* arow = attn + (size_t)(mt * 32 + lm) * 256 + lk;
    const __bf16* brow = woT + (size_t)(nc0 + lm) * 256 + lk;
#pragma unroll
    for (int kk = 0; kk < 8; ++kk) {
        bf16x8 a[2], b[4];
#pragma unroll
        for (int m = 0; m < 2; ++m) a[m] = *(const bf16x8*)(arow + (size_t)m * 16 * 256 + kk * 32);
#pragma unroll
        for (int n = 0; n < 4; ++n) b[n] = *(const bf16x8*)(brow + (size_t)n * 16 * 256 + kk * 32);
#pragma unroll
        for (int m = 0; m < 2; ++m)
#pragma unroll
            for (int n = 0; n < 4; ++n) acc[m][n] = mfma16(a[m], b[n], acc[m][n]);
    }
#pragma unroll
    for (int m = 0; m < 2; ++m) {
#pragma unroll
        for (int n = 0; n < 4; ++n) {
            int col = nc0 + n * 16 + lm;
#pragma unroll
            for (int r = 0; r < 4; ++r) {
                int row = mt * 32 + m * 16 + lg * 4 + r;
                out[(size_t)row * 256 + col] = acc[m][n][r];
            }
        }
    }
}

extern "C" void kernel_launch(void* const* d_in, const int* in_sizes, int n_in,
                              void* d_out, int out_size, void* d_ws, size_t ws_size,
                              hipStream_t stream) {
    const float* x    = (const float*)d_in[0];
    const float* Wq   = (const float*)d_in[1];
    const float* Wk   = (const float*)d_in[2];
    const float* Wv   = (const float*)d_in[3];
    const float* Wo   = (const float*)d_in[4];
    const float* bias = (const float*)d_in[5];
    float* out = (float*)d_out;

    __bf16* ws  = (__bf16*)d_ws;
    __bf16* xb  = ws;                       // 2,097,152 bf16 (reused as att)
    __bf16* wqT = xb  + 2097152;
    __bf16* wkT = wqT + 65536;
    __bf16* wvT = wkT + 65536;
    __bf16* woT = wvT + 65536;
    __bf16* qb  = woT + 65536;              // (b,h,n,32)
    __bf16* kb  = qb  + 2097152;            // (b,h) fragment-major K tiles
    __bf16* vb  = kb  + 2097152;            // (b,h) fragment-major V tiles
    __bf16* att = xb;                       // alias: xb dead after k_qkv

    k_prep<<<3072, 256, 0, stream>>>(x, Wq, Wk, Wv, Wo, xb, wqT, wkT, wvT, woT);
    k_qkv<<<1536, 64, 0, stream>>>(xb, wqT, wkT, wvT, qb, kb, vb);
    k_attn<<<1024, 256, 0, stream>>>(qb, kb, vb, bias, att);
    k_out<<<256, 256, 0, stream>>>(att, woT, out);
}

// Round 16
// 76.257 us; speedup vs baseline: 1.1852x; 1.0190x over previous
//
#include <hip/hip_runtime.h>
#include <math.h>

#define HIDDEN 256
#define NHEADS 8
#define HEAD 32
#define NTOK 2048      // tokens per batch (8*16*16)
#define NBIAS 115320   // 8 * 15 * 31 * 31
#define HTAB 14415     // 15*31*31 per-head bias entries

typedef __attribute__((ext_vector_type(8))) __bf16 bf16x8;
typedef __attribute__((ext_vector_type(4))) float f32x4;
typedef __attribute__((ext_vector_type(16))) float f32x16;
typedef __attribute__((ext_vector_type(4))) unsigned uint32x4;

static __device__ __forceinline__ f32x4 mfma16(bf16x8 a, bf16x8 b, f32x4 c) {
    return __builtin_amdgcn_mfma_f32_16x16x32_bf16(a, b, c, 0, 0, 0);
}
static __device__ __forceinline__ f32x16 mfma32(bf16x8 a, bf16x8 b, f32x16 c) {
    return __builtin_amdgcn_mfma_f32_32x32x16_bf16(a, b, c, 0, 0, 0);
}
static __device__ __forceinline__ float fexp2(float x) {
#if __has_builtin(__builtin_amdgcn_exp2f)
    return __builtin_amdgcn_exp2f(x);
#else
    return exp2f(x);
#endif
}
static __device__ __forceinline__ unsigned pkbf16(float a, float b) {
    unsigned short ua = __builtin_bit_cast(unsigned short, (__bf16)a);
    unsigned short ub = __builtin_bit_cast(unsigned short, (__bf16)b);
    return (unsigned)ua | ((unsigned)ub << 16);
}

// ---------------- kernel 0: fused input/weight conversion ----------------
__global__ void k_prep(const float* __restrict__ x, const float* __restrict__ w0,
                       const float* __restrict__ w1, const float* __restrict__ w2,
                       const float* __restrict__ w3, __bf16* __restrict__ xb,
                       __bf16* __restrict__ t0, __bf16* __restrict__ t1,
                       __bf16* __restrict__ t2, __bf16* __restrict__ t3) {
    int bid = blockIdx.x;
    if (bid < 2048) {
        int i = (bid * 256 + threadIdx.x) * 4;
        float4 v = *(const float4*)(x + i);
        uint2 pk = make_uint2(pkbf16(v.x, v.y), pkbf16(v.z, v.w));
        *(uint2*)(xb + i) = pk;                         // one 8B store (was 4x2B)
    } else {
        int q = bid - 2048;
        int wsel = q >> 8;
        int i = (q & 255) * 256 + threadIdx.x;
        const float* w = (wsel == 0) ? w0 : (wsel == 1) ? w1 : (wsel == 2) ? w2 : w3;
        __bf16* t = (wsel == 0) ? t0 : (wsel == 1) ? t1 : (wsel == 2) ? t2 : t3;
        int n = i >> 8, k = i & 255;
        t[i] = (__bf16)w[k * 256 + n];       // t[n][k] = W[k][n]
    }
}

// ---------------- kernel 1: fused QKV projection, 64x64 tile per 1-wave block --
// K/V in FRAGMENT-MAJOR tiled layouts (R7-verified); LDS-retiled coalesced stores.
__global__ __launch_bounds__(64) void k_qkv(const __bf16* __restrict__ xb,
                                            const __bf16* __restrict__ wqT,
                                            const __bf16* __restrict__ wkT,
                                            const __bf16* __restrict__ wvT,
                                            __bf16* __restrict__ qb,
                                            __bf16* __restrict__ kb,
                                            __bf16* __restrict__ vb) {
    int wid = blockIdx.x;                // 0..1535
    int lane = threadIdx.x;              // 0..63
    int ng = wid % 12, mt = wid / 12;    // mt 0..127
    int lm = lane & 15, lg = lane >> 4, lk = lg * 8;
    int which = ng >> 2;
    int nc0 = (ng & 3) * 64;
    const __bf16* wT = (which == 0) ? wqT : (which == 1) ? wkT : wvT;

    f32x4 acc[4][4];
#pragma unroll
    for (int m = 0; m < 4; ++m)
#pragma unroll
        for (int n = 0; n < 4; ++n) acc[m][n] = (f32x4){0.f, 0.f, 0.f, 0.f};

    const __bf16* arow = xb + (size_t)(mt * 64 + lm) * 256 + lk;
    const __bf16* brow = wT + (size_t)(nc0 + lm) * 256 + lk;
#pragma unroll
    for (int kk = 0; kk < 8; ++kk) {
        bf16x8 a[4], b[4];
#pragma unroll
        for (int m = 0; m < 4; ++m) a[m] = *(const bf16x8*)(arow + (size_t)m * 16 * 256 + kk * 32);
#pragma unroll
        for (int n = 0; n < 4; ++n) b[n] = *(const bf16x8*)(brow + (size_t)n * 16 * 256 + kk * 32);
#pragma unroll
        for (int m = 0; m < 4; ++m)
#pragma unroll
            for (int n = 0; n < 4; ++n) acc[m][n] = mfma16(a[m], b[n], acc[m][n]);
    }

    int b_ = mt >> 5;
    int tb = (mt & 31) * 2;
    int h0 = nc0 >> 5;

    __shared__ __attribute__((aligned(16))) __bf16 tile[4608];   // 64 x 72

    if (which == 0) {
        const float QS = 0.17677669529663687f * 1.4426950408889634f;  // 1/sqrt(32)*log2e
#pragma unroll
        for (int m = 0; m < 4; ++m)
#pragma unroll
            for (int n = 0; n < 4; ++n) {
                int col = nc0 + n * 16 + lm;
                int h = col >> 5, d = col & 31;
#pragma unroll
                for (int r = 0; r < 4; ++r) {
                    int row = mt * 64 + m * 16 + lg * 4 + r;
                    qb[(size_t)(b_ * 8 + h) * 65536 + (size_t)(row & 2047) * 32 + d] =
                        (__bf16)(acc[m][n][r] * QS);
                }
            }
        return;
    }

#pragma unroll
    for (int m = 0; m < 4; ++m)
#pragma unroll
        for (int n = 0; n < 4; ++n)
#pragma unroll
            for (int r = 0; r < 4; ++r) {
                int row = m * 16 + lg * 4 + r;
                int col = n * 16 + lm;
                if (which == 1) tile[row * 72 + col] = (__bf16)acc[m][n][r];
                else            tile[col * 72 + row] = (__bf16)acc[m][n][r];
            }
    __syncthreads();

    if (which == 1) {
#pragma unroll
        for (int tl = 0; tl < 2; ++tl)
#pragma unroll
            for (int hl = 0; hl < 2; ++hl) {
                size_t gb = (size_t)(b_ * 8 + h0 + hl) * 65536 + (size_t)(tb + tl) * 1024;
#pragma unroll
                for (int half = 0; half < 2; ++half) {
                    int u = half * 64 + lane;
                    int j = u >> 6, hf2 = (u >> 5) & 1, lq2 = u & 31;
                    bf16x8 vv = *(const bf16x8*)&tile[(tl * 32 + lq2) * 72 + hl * 32 + 16 * j + 8 * hf2];
                    *(bf16x8*)(kb + gb + (size_t)u * 8) = vv;
                }
            }
    } else {
#pragma unroll
        for (int tl = 0; tl < 2; ++tl)
#pragma unroll
            for (int hl = 0; hl < 2; ++hl) {
                size_t gb = (size_t)(b_ * 8 + h0 + hl) * 65536 + (size_t)(tb + tl) * 1024;
#pragma unroll
                for (int half = 0; half < 2; ++half) {
                    int u0 = (half * 64 + lane) * 2;
                    int g = u0 >> 6, hf2 = (u0 >> 5) & 1, d0 = u0 & 31;
                    const __bf16* pl = &tile[(hl * 32 + d0) * 72 + tl * 32 + 8 * g + 4 * hf2];
                    uint2 lo = *(const uint2*)pl;
                    uint2 hi = *(const uint2*)(pl + 72);
                    uint32x4 sv = {lo.x, lo.y, hi.x, hi.y};
                    *(uint32x4*)(vb + gb + (size_t)u0 * 4) = sv;
                }
            }
    }
}

// ---------------- kernel 2: attention (R13-proven: 45.8 us, VGPR 84) ------------
// Block = (b,h, 64 queries); wave = k-quarter x both strips; K/V frags shared.
// Bias slice 8x19x33 f32 in LDS, inline C-init read; lsum via ones-MFMA (Lacc).
__global__ __launch_bounds__(256) void k_attn(const __bf16* __restrict__ qb,
                                              const __bf16* __restrict__ kb,
                                              const __bf16* __restrict__ vb,
                                              const float* __restrict__ bias,
                                              __bf16* __restrict__ attn) {
    int i = blockIdx.x;
    int x = i & 7, r_ = i >> 3;          // XCD x serves bh {x,x+8,x+16,x+24}
    int bh = x + ((r_ >> 5) << 3);
    int qblk = r_ & 31;
    int b_ = bh >> 3, h = bh & 7;
    int w = threadIdx.x >> 6;
    int lane = threadIdx.x & 63;
    int lq = lane & 31;
    int hf = lane >> 5;
    int q0 = qblk * 64;

    __shared__ float smem[5016];   // bias slice 8*19*33; unions part[4][64][17]=4352

    {
        int qd = q0 >> 8, qh0 = (q0 >> 4) & 15;
        const float* bt = bias + h * HTAB;
        for (int t = threadIdx.x; t < 5016; t += 256) {
            int dd = t / 627, rem = t - dd * 627;
            int hh = rem / 33, ww = rem - hh * 33;
            int dw = 30 - ww; if (dw < 0) dw = 0;
            smem[t] = bt[(qd + dd) * 961 + (qh0 + hh) * 31 + dw] * 1.4426950408889634f;
        }
    }
    __syncthreads();

    const __bf16* qbase = qb + (size_t)bh * NTOK * 32;
    const __bf16* kbase = kb + (size_t)bh * NTOK * 32;
    const __bf16* vbase = vb + (size_t)bh * NTOK * 32;

    bf16x8 qfA0 = *(const bf16x8*)(qbase + (size_t)(q0 + lq) * 32 + hf * 8);
    bf16x8 qfA1 = *(const bf16x8*)(qbase + (size_t)(q0 + lq) * 32 + 16 + hf * 8);
    bf16x8 qfB0 = *(const bf16x8*)(qbase + (size_t)(q0 + 32 + lq) * 32 + hf * 8);
    bf16x8 qfB1 = *(const bf16x8*)(qbase + (size_t)(q0 + 32 + lq) * 32 + 16 + hf * 8);

    int lbase = (lq >> 4) * 33 + 15 - (lq & 15) + 4 * hf;

    f32x16 OaccA, LaccA, OaccB, LaccB;
#pragma unroll
    for (int j = 0; j < 16; ++j) { OaccA[j] = 0.f; LaccA[j] = 0.f; OaccB[j] = 0.f; LaccB[j] = 0.f; }

    bf16x8 ones;
#pragma unroll
    for (int j = 0; j < 8; ++j) ones[j] = (__bf16)1.0f;

    // K-frag pipeline registers
    bf16x8 ck0, ck1;
    {
        const __bf16* kt = kbase + ((size_t)(w * 16) * 128 + lane) * 8;
        ck0 = *(const bf16x8*)(kt);
        ck1 = *(const bf16x8*)(kt + 512);
    }

#pragma unroll
    for (int it = 0; it < 16; ++it) {
        int t0 = w * 512 + it * 32;
        int tt = t0 >> 5;

        // prefetch next K frags
        bf16x8 nk0, nk1;
        if (it < 15) {
            const __bf16* kt1 = kbase + ((size_t)(tt + 1) * 128 + lane) * 8;
            nk0 = *(const bf16x8*)(kt1);
            nk1 = *(const bf16x8*)(kt1 + 512);
        }

        // V frags (contiguous), shared by both strips
        const __bf16* vt = vbase + ((size_t)tt * 256 + lane) * 4;
        uint2 va  = *(const uint2*)(vt);
        uint2 vbq = *(const uint2*)(vt + 256);
        uint2 vc  = *(const uint2*)(vt + 512);
        uint2 vd  = *(const uint2*)(vt + 768);
        uint32x4 vw0 = {va.x, va.y, vbq.x, vbq.y};
        uint32x4 vw1 = {vc.x, vc.y, vd.x, vd.y};
        bf16x8 vf0 = __builtin_bit_cast(bf16x8, vw0);
        bf16x8 vf1 = __builtin_bit_cast(bf16x8, vw1);

        // bias C-init from LDS (inline)
        int kd = t0 >> 8, kh0 = (t0 >> 4) & 15;
        int a0 = (7 - kd) * 627 + (15 - kh0) * 33 + lbase;
        f32x16 SA, SB;
#pragma unroll
        for (int r = 0; r < 4; ++r) {
            SA[r]      = smem[a0 + r];
            SA[4 + r]  = smem[a0 + 8 + r];
            SA[8 + r]  = smem[a0 - 33 + r];
            SA[12 + r] = smem[a0 - 25 + r];
            SB[r]      = smem[a0 + 66 + r];
            SB[4 + r]  = smem[a0 + 74 + r];
            SB[8 + r]  = smem[a0 + 33 + r];
            SB[12 + r] = smem[a0 + 41 + r];
        }
        SA = mfma32(ck0, qfA0, SA);
        SA = mfma32(ck1, qfA1, SA);
        SB = mfma32(ck0, qfB0, SB);
        SB = mfma32(ck1, qfB1, SB);

        // strip A
        {
            unsigned W0 = pkbf16(fexp2(SA[0]),  fexp2(SA[1]));
            unsigned W1 = pkbf16(fexp2(SA[2]),  fexp2(SA[3]));
            unsigned W2 = pkbf16(fexp2(SA[4]),  fexp2(SA[5]));
            unsigned W3 = pkbf16(fexp2(SA[6]),  fexp2(SA[7]));
            unsigned W4 = pkbf16(fexp2(SA[8]),  fexp2(SA[9]));
            unsigned W5 = pkbf16(fexp2(SA[10]), fexp2(SA[11]));
            unsigned W6 = pkbf16(fexp2(SA[12]), fexp2(SA[13]));
            unsigned W7 = pkbf16(fexp2(SA[14]), fexp2(SA[15]));
            uint32x4 pw0 = {W0, W1, W2, W3};
            uint32x4 pw1 = {W4, W5, W6, W7};
            bf16x8 pf0 = __builtin_bit_cast(bf16x8, pw0);
            bf16x8 pf1 = __builtin_bit_cast(bf16x8, pw1);
            OaccA = mfma32(vf0, pf0, OaccA);
            OaccA = mfma32(vf1, pf1, OaccA);
            LaccA = mfma32(ones, pf0, LaccA);
            LaccA = mfma32(ones, pf1, LaccA);
        }
        // strip B
        {
            unsigned W0 = pkbf16(fexp2(SB[0]),  fexp2(SB[1]));
            unsigned W1 = pkbf16(fexp2(SB[2]),  fexp2(SB[3]));
            unsigned W2 = pkbf16(fexp2(SB[4]),  fexp2(SB[5]));
            unsigned W3 = pkbf16(fexp2(SB[6]),  fexp2(SB[7]));
            unsigned W4 = pkbf16(fexp2(SB[8]),  fexp2(SB[9]));
            unsigned W5 = pkbf16(fexp2(SB[10]), fexp2(SB[11]));
            unsigned W6 = pkbf16(fexp2(SB[12]), fexp2(SB[13]));
            unsigned W7 = pkbf16(fexp2(SB[14]), fexp2(SB[15]));
            uint32x4 pw0 = {W0, W1, W2, W3};
            uint32x4 pw1 = {W4, W5, W6, W7};
            bf16x8 pf0 = __builtin_bit_cast(bf16x8, pw0);
            bf16x8 pf1 = __builtin_bit_cast(bf16x8, pw1);
            OaccB = mfma32(vf0, pf0, OaccB);
            OaccB = mfma32(vf1, pf1, OaccB);
            LaccB = mfma32(ones, pf0, LaccB);
            LaccB = mfma32(ones, pf1, LaccB);
        }

        if (it < 15) { ck0 = nk0; ck1 = nk1; }
    }

    // ---- combine 4 k-partials via LDS (reuse smem as part[4][64][17]) ----
    float (*part)[64][17] = (float (*)[64][17])smem;
#pragma unroll
    for (int s = 0; s < 2; ++s) {
        f32x16* O = s ? &OaccB : &OaccA;
        f32x16* L = s ? &LaccB : &LaccA;
        __syncthreads();
#pragma unroll
        for (int j = 0; j < 4; ++j) {
            float4 t;
            t.x = (*O)[4 * j]; t.y = (*O)[4 * j + 1]; t.z = (*O)[4 * j + 2]; t.w = (*O)[4 * j + 3];
            *(float4*)&part[w][lane][4 * j] = t;
        }
        part[w][lane][16] = (*L)[0];
        __syncthreads();

        float4 o = {0.f, 0.f, 0.f, 0.f};
        float ls = 0.f;
#pragma unroll
        for (int sw = 0; sw < 4; ++sw) {
            float4 t = *(const float4*)&part[sw][lane][4 * w];
            o.x += t.x; o.y += t.y; o.z += t.z; o.w += t.w;
            ls += part[sw][lane][16];
        }
        float inv = 1.0f / ls;
        unsigned lo = pkbf16(o.x * inv, o.y * inv);
        unsigned hi = pkbf16(o.z * inv, o.w * inv);
        size_t base = ((size_t)b_ * NTOK + q0 + 32 * s + lq) * 256 + h * 32 + 8 * w + 4 * hf;
        *(uint2*)(attn + base) = make_uint2(lo, hi);
    }
}

// ---------------- kernel 3: output projection -> fp32, 32x64 tile per wave ------
__global__ __launch_bounds__(256) void k_out(const __bf16* __restrict__ attn,
                                             const __bf16* __restrict__ woT,
                                             float* __restrict__ out) {
    int wid = blockIdx.x * 4 + (threadIdx.x >> 6);   // 0..1023
    int lane = threadIdx.x & 63;
    int ng = wid & 3, mt = wid >> 2;                 // mt 0..255
    int lm = lane & 15, lg = lane >> 4, lk = lg * 8;
    int nc0 = ng * 64;

    f32x4 acc[2][4];
#pragma unroll
    for (int m = 0; m < 2; ++m)
#pragma unroll
        for (int n = 0; n < 4; ++n) acc[m][n] = (f32x4){0.f, 0.f, 0.f, 0.f};

    const __bf16* arow = attn + (size_t)(mt * 32 + lm) * 256 + lk;
    const __bf16* brow = woT + (size_t)(nc0 + lm) * 256 + lk;
#pragma unroll
    for (int kk = 0; kk < 8; ++kk) {
        bf16x8 a[2], b[4];
#pragma unroll
        for (int m = 0; m < 2; ++m) a[m] = *(const bf16x8*)(arow + (size_t)m * 16 * 256 + kk * 32);
#pragma unroll
        for (int n = 0; n < 4; ++n) b[n] = *(const bf16x8*)(brow + (size_t)n * 16 * 256 + kk * 32);
#pragma unroll
        for (int m = 0; m < 2; ++m)
#pragma unroll
            for (int n = 0; n < 4; ++n) acc[m][n] = mfma16(a[m], b[n], acc[m][n]);
    }
#pragma unroll
    for (int m = 0; m < 2; ++m) {
#pragma unroll
        for (int n = 0; n < 4; ++n) {
            int col = nc0 + n * 16 + lm;
#pragma unroll
            for (int r = 0; r < 4; ++r) {
                int row = mt * 32 + m * 16 + lg * 4 + r;
                out[(size_t)row * 256 + col] = acc[m][n][r];
            }
        }
    }
}

extern "C" void kernel_launch(void* const* d_in, const int* in_sizes, int n_in,
                              void* d_out, int out_size, void* d_ws, size_t ws_size,
                              hipStream_t stream) {
    const float* x    = (const float*)d_in[0];
    const float* Wq   = (const float*)d_in[1];
    const float* Wk   = (const float*)d_in[2];
    const float* Wv   = (const float*)d_in[3];
    const float* Wo   = (const float*)d_in[4];
    const float* bias = (const float*)d_in[5];
    float* out = (float*)d_out;

    __bf16* ws  = (__bf16*)d_ws;
    __bf16* xb  = ws;                       // 2,097,152 bf16 (reused as att)
    __bf16* wqT = xb  + 2097152;
    __bf16* wkT = wqT + 65536;
    __bf16* wvT = wkT + 65536;
    __bf16* woT = wvT + 65536;
    __bf16* qb  = woT + 65536;              // (b,h,n,32)
    __bf16* kb  = qb  + 2097152;            // (b,h) fragment-major K tiles
    __bf16* vb  = kb  + 2097152;            // (b,h) fragment-major V tiles
    __bf16* att = xb;                       // alias: xb dead after k_qkv

    k_prep<<<3072, 256, 0, stream>>>(x, Wq, Wk, Wv, Wo, xb, wqT, wkT, wvT, woT);
    k_qkv<<<1536, 64, 0, stream>>>(xb, wqT, wkT, wvT, qb, kb, vb);
    k_attn<<<1024, 256, 0, stream>>>(qb, kb, vb, bias, att);
    k_out<<<256, 256, 0, stream>>>(att, woT, out);
}